// Round 1
// baseline (1499.437 us; speedup 1.0000x reference)
//
#include <hip/hip_runtime.h>
#include <math.h>

// Problem constants
constexpr int kB     = 4;
constexpr int kH     = 48;
constexpr int kW     = 48;
constexpr int kHW    = 2304;   // 48*48
constexpr int kC     = 256;
constexpr int kHeads = 8;
constexpr int kHD    = 32;
constexpr float kScale = 0.17677669529663687f;  // 32^-0.5

// ---------------------------------------------------------------------------
// Kernel 1: fused QKV projection GEMM (fp32, LDS-tiled 64x64x16)
// out layout: head-major (B, HEADS, HW, HD). k is pre-scaled by kScale.
// ---------------------------------------------------------------------------
__global__ __launch_bounds__(256) void qkv_gemm_kernel(
    const float* __restrict__ x,
    const float* __restrict__ Wq, const float* __restrict__ bq,
    const float* __restrict__ Wk, const float* __restrict__ bk,
    const float* __restrict__ Wv, const float* __restrict__ bv,
    float* __restrict__ qb, float* __restrict__ kb, float* __restrict__ vb)
{
    const int z = blockIdx.z;
    const float* Wt = (z == 0) ? Wq : ((z == 1) ? Wk : Wv);
    const float* bt = (z == 0) ? bq : ((z == 1) ? bk : bv);
    float* ob       = (z == 0) ? qb : ((z == 1) ? kb : vb);
    const float oscale = (z == 1) ? kScale : 1.0f;

    __shared__ __align__(16) float As[16][65];  // [k][m]
    __shared__ __align__(16) float Bs[16][65];  // [k][n]

    const int tid = threadIdx.x;
    const int mBase = blockIdx.x * 64;
    const int nBase = blockIdx.y * 64;

    const int tx = tid & 15;
    const int ty = tid >> 4;

    // A-load indices: row lm (0..63), 4 consecutive k at lk
    const int lm  = tid >> 2;
    const int lk  = (tid & 3) * 4;
    // B-load indices: k row lbk (0..15), 4 consecutive n at lbn
    const int lbk = tid >> 4;
    const int lbn = (tid & 15) * 4;

    float acc[4][4] = {};

    for (int k0 = 0; k0 < 256; k0 += 16) {
        const float4 av = *reinterpret_cast<const float4*>(
            &x[(size_t)(mBase + lm) * 256 + k0 + lk]);
        As[lk + 0][lm] = av.x; As[lk + 1][lm] = av.y;
        As[lk + 2][lm] = av.z; As[lk + 3][lm] = av.w;

        const float4 bv4 = *reinterpret_cast<const float4*>(
            &Wt[(size_t)(k0 + lbk) * 256 + nBase + lbn]);
        Bs[lbk][lbn + 0] = bv4.x; Bs[lbk][lbn + 1] = bv4.y;
        Bs[lbk][lbn + 2] = bv4.z; Bs[lbk][lbn + 3] = bv4.w;
        __syncthreads();

        #pragma unroll
        for (int kk = 0; kk < 16; ++kk) {
            float a[4], bb[4];
            #pragma unroll
            for (int i = 0; i < 4; ++i) a[i] = As[kk][ty * 4 + i];
            #pragma unroll
            for (int j = 0; j < 4; ++j) bb[j] = Bs[kk][tx * 4 + j];
            #pragma unroll
            for (int i = 0; i < 4; ++i)
                #pragma unroll
                for (int j = 0; j < 4; ++j)
                    acc[i][j] += a[i] * bb[j];
        }
        __syncthreads();
    }

    #pragma unroll
    for (int i = 0; i < 4; ++i) {
        const int m  = mBase + ty * 4 + i;
        const int b  = m / kHW;
        const int hw = m % kHW;
        #pragma unroll
        for (int j = 0; j < 4; ++j) {
            const int n    = nBase + tx * 4 + j;
            const int head = n >> 5;
            const int d    = n & 31;
            ob[(((size_t)(b * kHeads + head) * kHW + hw) << 5) + d] =
                (acc[i][j] + bt[n]) * oscale;
        }
    }
}

// ---------------------------------------------------------------------------
// Kernel 2: RoPE-style angle transform, in-place on q and k (pair per thread)
// ---------------------------------------------------------------------------
__global__ __launch_bounds__(256) void rope_kernel(
    float* __restrict__ qb, float* __restrict__ kb,
    const float* __restrict__ sinb, const float* __restrict__ cosb)
{
    const int total_pairs = kB * kHeads * kHW * kHD / 2;  // 1179648
    int gid = blockIdx.x * blockDim.x + threadIdx.x;
    float* buf = qb;
    if (gid >= total_pairs) { buf = kb; gid -= total_pairs; }

    const int e0 = gid * 2;
    const int d  = e0 & 31;               // even
    const int hw = (e0 >> 5) % kHW;

    const float c0 = cosb[hw * 32 + d];
    const float s0 = sinb[hw * 32 + d];
    const float c1 = cosb[hw * 32 + d + 1];
    const float s1 = sinb[hw * 32 + d + 1];

    float2 v = *reinterpret_cast<float2*>(&buf[e0]);
    float2 r;
    r.x = v.x * c0 - v.y * s0;   // rot[even] = -x[odd]
    r.y = v.y * c1 + v.x * s1;   // rot[odd]  =  x[even]
    *reinterpret_cast<float2*>(&buf[e0]) = r;
}

// ---------------------------------------------------------------------------
// Kernel 3: LePE 5x5 depthwise conv on v (head-major in, token-major out)
// ---------------------------------------------------------------------------
__global__ __launch_bounds__(256) void lepe_kernel(
    const float* __restrict__ vb,
    const float* __restrict__ lw, const float* __restrict__ lb,
    float* __restrict__ lepe)
{
    const int c   = threadIdx.x;
    const int bhw = blockIdx.x;
    const int b   = bhw / kHW;
    const int hw  = bhw % kHW;
    const int h   = hw / kW;
    const int w   = hw % kW;
    const int head = c >> 5;
    const int d    = c & 31;

    const float* vsrc = vb + ((size_t)(b * kHeads + head) * kHW) * kHD + d;
    float acc = lb[c];
    #pragma unroll
    for (int dh = 0; dh < 5; ++dh) {
        const int h2 = h + dh - 2;
        if (h2 < 0 || h2 >= kH) continue;
        #pragma unroll
        for (int dw = 0; dw < 5; ++dw) {
            const int w2 = w + dw - 2;
            if (w2 < 0 || w2 >= kW) continue;
            acc += vsrc[(size_t)(h2 * kW + w2) * kHD] * lw[(dh * 5 + dw) * kC + c];
        }
    }
    lepe[(size_t)bhw * kC + c] = acc;
}

// ---------------------------------------------------------------------------
// Kernel 4: flash-style attention, fp32.
// grid (36 q-tiles, 32 b*head), block 256.
// Each thread: row r = tid>>2 (64 rows), quarter qd = tid&3 (16 cols each).
// q-row + full 32-dim accumulator in registers (4x redundant across quarter),
// online softmax, shfl reductions within the 4-lane row group.
// ---------------------------------------------------------------------------
__global__ __launch_bounds__(256) void attn_kernel(
    const float* __restrict__ qb, const float* __restrict__ kb,
    const float* __restrict__ vb, const float* __restrict__ mask,
    float* __restrict__ attn_out)
{
    const int bh   = blockIdx.y;          // b*8+head
    const int b    = bh >> 3;
    const int head = bh & 7;
    const int qt   = blockIdx.x;
    const int tid  = threadIdx.x;
    const int r    = tid >> 2;
    const int qd   = tid & 3;

    __shared__ __align__(16) float Ks[64][36];
    __shared__ __align__(16) float Vs[64][36];

    const size_t basebh = (size_t)bh * kHW * kHD;
    const int qrow0 = qt * 64;
    const int row   = qrow0 + r;

    // q row -> registers (4 threads/row read redundantly; L1/L2 absorbs)
    float qreg[32];
    #pragma unroll
    for (int k4 = 0; k4 < 8; ++k4) {
        const float4 qv = *reinterpret_cast<const float4*>(
            &qb[basebh + (size_t)row * kHD + k4 * 4]);
        qreg[k4 * 4 + 0] = qv.x; qreg[k4 * 4 + 1] = qv.y;
        qreg[k4 * 4 + 2] = qv.z; qreg[k4 * 4 + 3] = qv.w;
    }

    float m_run = -1e30f, l_run = 0.0f;
    float acc[32] = {};

    const float* mrow = mask + ((size_t)head * kHW + row) * kHW;

    // staging indices
    const int lr = tid >> 2;
    const int ld = (tid & 3) * 8;

    for (int kt = 0; kt < 36; ++kt) {
        __syncthreads();   // previous iteration's reads done before overwrite
        {
            const size_t off = basebh + (size_t)(kt * 64 + lr) * kHD + ld;
            *reinterpret_cast<float4*>(&Ks[lr][ld])     = *reinterpret_cast<const float4*>(&kb[off]);
            *reinterpret_cast<float4*>(&Ks[lr][ld + 4]) = *reinterpret_cast<const float4*>(&kb[off + 4]);
            *reinterpret_cast<float4*>(&Vs[lr][ld])     = *reinterpret_cast<const float4*>(&vb[off]);
            *reinterpret_cast<float4*>(&Vs[lr][ld + 4]) = *reinterpret_cast<const float4*>(&vb[off + 4]);
        }
        __syncthreads();

        const int c0 = qd * 16;
        float s[16];
        // scores (dot over 32) + mask
        {
            const float4 mv0 = *reinterpret_cast<const float4*>(&mrow[kt * 64 + c0 + 0]);
            const float4 mv1 = *reinterpret_cast<const float4*>(&mrow[kt * 64 + c0 + 4]);
            const float4 mv2 = *reinterpret_cast<const float4*>(&mrow[kt * 64 + c0 + 8]);
            const float4 mv3 = *reinterpret_cast<const float4*>(&mrow[kt * 64 + c0 + 12]);
            const float mvals[16] = {mv0.x, mv0.y, mv0.z, mv0.w,
                                     mv1.x, mv1.y, mv1.z, mv1.w,
                                     mv2.x, mv2.y, mv2.z, mv2.w,
                                     mv3.x, mv3.y, mv3.z, mv3.w};
            #pragma unroll
            for (int j = 0; j < 16; ++j) {
                const float* krow = &Ks[c0 + j][0];
                float sj = 0.0f;
                #pragma unroll
                for (int k4 = 0; k4 < 8; ++k4) {
                    const float4 kv = *reinterpret_cast<const float4*>(&krow[k4 * 4]);
                    sj += qreg[k4 * 4 + 0] * kv.x + qreg[k4 * 4 + 1] * kv.y +
                          qreg[k4 * 4 + 2] * kv.z + qreg[k4 * 4 + 3] * kv.w;
                }
                s[j] = sj + mvals[j];
            }
        }
        // online softmax update
        float mx = s[0];
        #pragma unroll
        for (int j = 1; j < 16; ++j) mx = fmaxf(mx, s[j]);
        mx = fmaxf(mx, __shfl_xor(mx, 1));
        mx = fmaxf(mx, __shfl_xor(mx, 2));
        const float newm  = fmaxf(m_run, mx);
        const float alpha = __expf(m_run - newm);
        float p[16];
        float psum = 0.0f;
        #pragma unroll
        for (int j = 0; j < 16; ++j) { p[j] = __expf(s[j] - newm); psum += p[j]; }
        psum += __shfl_xor(psum, 1);
        psum += __shfl_xor(psum, 2);
        l_run = l_run * alpha + psum;
        m_run = newm;

        #pragma unroll
        for (int dd = 0; dd < 32; ++dd) acc[dd] *= alpha;
        #pragma unroll
        for (int j = 0; j < 16; ++j) {
            const float pj = p[j];
            const float* vrow = &Vs[c0 + j][0];
            #pragma unroll
            for (int d4 = 0; d4 < 8; ++d4) {
                const float4 vv = *reinterpret_cast<const float4*>(&vrow[d4 * 4]);
                acc[d4 * 4 + 0] += pj * vv.x; acc[d4 * 4 + 1] += pj * vv.y;
                acc[d4 * 4 + 2] += pj * vv.z; acc[d4 * 4 + 3] += pj * vv.w;
            }
        }
    }

    // combine the 4 quarter-partials of each row
    #pragma unroll
    for (int dd = 0; dd < 32; ++dd) {
        acc[dd] += __shfl_xor(acc[dd], 1);
        acc[dd] += __shfl_xor(acc[dd], 2);
    }
    const float inv_l = 1.0f / l_run;

    // write 8 dims per thread, token-major (B, HW, C)
    float* orow = attn_out + ((size_t)b * kHW + row) * kC + head * kHD;
    #pragma unroll
    for (int jj = 0; jj < 8; ++jj)
        orow[qd * 8 + jj] = acc[qd * 8 + jj] * inv_l;
}

// ---------------------------------------------------------------------------
// Kernel 5: output projection GEMM, fusing (attn_out + lepe) @ Wout + bout
// ---------------------------------------------------------------------------
__global__ __launch_bounds__(256) void out_gemm_kernel(
    const float* __restrict__ a0, const float* __restrict__ a1,
    const float* __restrict__ Wo, const float* __restrict__ bo,
    float* __restrict__ out)
{
    __shared__ __align__(16) float As[16][65];
    __shared__ __align__(16) float Bs[16][65];

    const int tid = threadIdx.x;
    const int mBase = blockIdx.x * 64;
    const int nBase = blockIdx.y * 64;

    const int tx = tid & 15;
    const int ty = tid >> 4;

    const int lm  = tid >> 2;
    const int lk  = (tid & 3) * 4;
    const int lbk = tid >> 4;
    const int lbn = (tid & 15) * 4;

    float acc[4][4] = {};

    for (int k0 = 0; k0 < 256; k0 += 16) {
        const size_t aoff = (size_t)(mBase + lm) * 256 + k0 + lk;
        const float4 av0 = *reinterpret_cast<const float4*>(&a0[aoff]);
        const float4 av1 = *reinterpret_cast<const float4*>(&a1[aoff]);
        As[lk + 0][lm] = av0.x + av1.x; As[lk + 1][lm] = av0.y + av1.y;
        As[lk + 2][lm] = av0.z + av1.z; As[lk + 3][lm] = av0.w + av1.w;

        const float4 bv4 = *reinterpret_cast<const float4*>(
            &Wo[(size_t)(k0 + lbk) * 256 + nBase + lbn]);
        Bs[lbk][lbn + 0] = bv4.x; Bs[lbk][lbn + 1] = bv4.y;
        Bs[lbk][lbn + 2] = bv4.z; Bs[lbk][lbn + 3] = bv4.w;
        __syncthreads();

        #pragma unroll
        for (int kk = 0; kk < 16; ++kk) {
            float a[4], bb[4];
            #pragma unroll
            for (int i = 0; i < 4; ++i) a[i] = As[kk][ty * 4 + i];
            #pragma unroll
            for (int j = 0; j < 4; ++j) bb[j] = Bs[kk][tx * 4 + j];
            #pragma unroll
            for (int i = 0; i < 4; ++i)
                #pragma unroll
                for (int j = 0; j < 4; ++j)
                    acc[i][j] += a[i] * bb[j];
        }
        __syncthreads();
    }

    #pragma unroll
    for (int i = 0; i < 4; ++i) {
        const int m = mBase + ty * 4 + i;
        #pragma unroll
        for (int j = 0; j < 4; ++j) {
            const int n = nBase + tx * 4 + j;
            out[(size_t)m * 256 + n] = acc[i][j] + bo[n];
        }
    }
}

// ---------------------------------------------------------------------------
extern "C" void kernel_launch(void* const* d_in, const int* in_sizes, int n_in,
                              void* d_out, int out_size, void* d_ws, size_t ws_size,
                              hipStream_t stream)
{
    const float* x    = (const float*)d_in[0];
    const float* sinb = (const float*)d_in[1];
    const float* cosb = (const float*)d_in[2];
    const float* mask = (const float*)d_in[3];
    const float* Wq   = (const float*)d_in[4];
    const float* bq   = (const float*)d_in[5];
    const float* Wk   = (const float*)d_in[6];
    const float* bk   = (const float*)d_in[7];
    const float* Wv   = (const float*)d_in[8];
    const float* bv   = (const float*)d_in[9];
    const float* lw   = (const float*)d_in[10];
    const float* lb   = (const float*)d_in[11];
    const float* Wo   = (const float*)d_in[12];
    const float* bo   = (const float*)d_in[13];
    float* out = (float*)d_out;

    float* ws = (float*)d_ws;
    const size_t NT = (size_t)kB * kHeads * kHW * kHD;  // 2359296 per tensor
    float* qb   = ws;
    float* kb   = ws + NT;
    float* vb   = ws + 2 * NT;
    float* lepe = ws + 3 * NT;
    float* ao   = ws + 4 * NT;

    qkv_gemm_kernel<<<dim3(144, 4, 3), 256, 0, stream>>>(x, Wq, bq, Wk, bk, Wv, bv, qb, kb, vb);
    rope_kernel<<<dim3(9216), 256, 0, stream>>>(qb, kb, sinb, cosb);
    lepe_kernel<<<dim3(9216), 256, 0, stream>>>(vb, lw, lb, lepe);
    attn_kernel<<<dim3(36, 32), 256, 0, stream>>>(qb, kb, vb, mask, ao);
    out_gemm_kernel<<<dim3(144, 4), 256, 0, stream>>>(ao, lepe, Wo, bo, out);
}

// Round 2
// 348.334 us; speedup vs baseline: 4.3046x; 4.3046x over previous
//
#include <hip/hip_runtime.h>
#include <hip/hip_bf16.h>
#include <math.h>

// Problem constants
constexpr int kB     = 4;
constexpr int kH     = 48;
constexpr int kW     = 48;
constexpr int kHW    = 2304;   // 48*48
constexpr int kC     = 256;
constexpr int kHeads = 8;
constexpr int kHD    = 32;
constexpr float kScale = 0.17677669529663687f;  // 32^-0.5

typedef __bf16 bf16x8 __attribute__((ext_vector_type(8)));
typedef float  f32x4  __attribute__((ext_vector_type(4)));
typedef unsigned int   uint32x4 __attribute__((ext_vector_type(4)));
typedef unsigned short ushort8v __attribute__((ext_vector_type(8)));

static __device__ __forceinline__ unsigned short f2bf_bits(float f) {
    return __builtin_bit_cast(unsigned short, __float2bfloat16(f));
}

// ---------------------------------------------------------------------------
// Kernel 1: fused QKV projection GEMM (fp32 compute, LDS-tiled 64x64x16)
// z=0 -> q (RoPE'd, bf16, head-major), z=1 -> k (scaled+RoPE'd, bf16),
// z=2 -> v (fp32, head-major, feeds lepe + transpose).
// ---------------------------------------------------------------------------
__global__ __launch_bounds__(256) void qkv_gemm_kernel(
    const float* __restrict__ x,
    const float* __restrict__ Wq, const float* __restrict__ bq,
    const float* __restrict__ Wk, const float* __restrict__ bk,
    const float* __restrict__ Wv, const float* __restrict__ bv,
    const float* __restrict__ sinb, const float* __restrict__ cosb,
    __hip_bfloat16* __restrict__ qbh, __hip_bfloat16* __restrict__ kbh,
    float* __restrict__ vb)
{
    const int z = blockIdx.z;
    const float* Wt = (z == 0) ? Wq : ((z == 1) ? Wk : Wv);
    const float* bt = (z == 0) ? bq : ((z == 1) ? bk : bv);

    __shared__ __align__(16) float As[16][65];  // [k][m]
    __shared__ __align__(16) float Bs[16][65];  // [k][n]

    const int tid = threadIdx.x;
    const int mBase = blockIdx.x * 64;
    const int nBase = blockIdx.y * 64;

    const int tx = tid & 15;
    const int ty = tid >> 4;

    const int lm  = tid >> 2;
    const int lk  = (tid & 3) * 4;
    const int lbk = tid >> 4;
    const int lbn = (tid & 15) * 4;

    float acc[4][4] = {};

    for (int k0 = 0; k0 < 256; k0 += 16) {
        const float4 av = *reinterpret_cast<const float4*>(
            &x[(size_t)(mBase + lm) * 256 + k0 + lk]);
        As[lk + 0][lm] = av.x; As[lk + 1][lm] = av.y;
        As[lk + 2][lm] = av.z; As[lk + 3][lm] = av.w;

        const float4 bv4 = *reinterpret_cast<const float4*>(
            &Wt[(size_t)(k0 + lbk) * 256 + nBase + lbn]);
        Bs[lbk][lbn + 0] = bv4.x; Bs[lbk][lbn + 1] = bv4.y;
        Bs[lbk][lbn + 2] = bv4.z; Bs[lbk][lbn + 3] = bv4.w;
        __syncthreads();

        #pragma unroll
        for (int kk = 0; kk < 16; ++kk) {
            float a[4], bb[4];
            #pragma unroll
            for (int i = 0; i < 4; ++i) a[i] = As[kk][ty * 4 + i];
            #pragma unroll
            for (int j = 0; j < 4; ++j) bb[j] = Bs[kk][tx * 4 + j];
            #pragma unroll
            for (int i = 0; i < 4; ++i)
                #pragma unroll
                for (int j = 0; j < 4; ++j)
                    acc[i][j] += a[i] * bb[j];
        }
        __syncthreads();
    }

    const int n0   = nBase + tx * 4;
    const int head = n0 >> 5;
    const int d0   = n0 & 31;
    const float scl = (z == 1) ? kScale : 1.0f;

    #pragma unroll
    for (int i = 0; i < 4; ++i) {
        const int m  = mBase + ty * 4 + i;
        const int b  = m / kHW;
        const int hw = m % kHW;
        float t0 = (acc[i][0] + bt[n0 + 0]) * scl;
        float t1 = (acc[i][1] + bt[n0 + 1]) * scl;
        float t2 = (acc[i][2] + bt[n0 + 2]) * scl;
        float t3 = (acc[i][3] + bt[n0 + 3]) * scl;

        if (z == 2) {
            float* vr = vb + (((size_t)(b * kHeads + head) * kHW + hw) << 5) + d0;
            vr[0] = t0; vr[1] = t1; vr[2] = t2; vr[3] = t3;
        } else {
            const float* cs = cosb + hw * 32 + d0;
            const float* sn = sinb + hw * 32 + d0;
            const float r0 = t0 * cs[0] - t1 * sn[0];
            const float r1 = t1 * cs[1] + t0 * sn[1];
            const float r2 = t2 * cs[2] - t3 * sn[2];
            const float r3 = t3 * cs[3] + t2 * sn[3];
            __hip_bfloat16* ob = (z == 0) ? qbh : kbh;
            alignas(8) unsigned short u[4] = {f2bf_bits(r0), f2bf_bits(r1),
                                              f2bf_bits(r2), f2bf_bits(r3)};
            *reinterpret_cast<unsigned long long*>(
                reinterpret_cast<unsigned short*>(ob) +
                (((size_t)(b * kHeads + head) * kHW + hw) << 5) + d0) =
                *reinterpret_cast<unsigned long long*>(u);
        }
    }
}

// ---------------------------------------------------------------------------
// Kernel 2: transpose v (fp32 head-major [bh][hw][32]) -> vt bf16 [bh][32][hw]
// ---------------------------------------------------------------------------
__global__ __launch_bounds__(256) void vt_kernel(
    const float* __restrict__ vb, __hip_bfloat16* __restrict__ vt)
{
    __shared__ float lds[64][33];
    const int bh  = blockIdx.y;
    const int hw0 = blockIdx.x * 64;
    const int t   = threadIdx.x;

    const int hl = t >> 2, dq = (t & 3) * 8;
    const float* src = vb + ((size_t)bh * kHW + hw0 + hl) * 32 + dq;
    const float4 a = *reinterpret_cast<const float4*>(src);
    const float4 b = *reinterpret_cast<const float4*>(src + 4);
    lds[hl][dq + 0] = a.x; lds[hl][dq + 1] = a.y;
    lds[hl][dq + 2] = a.z; lds[hl][dq + 3] = a.w;
    lds[hl][dq + 4] = b.x; lds[hl][dq + 5] = b.y;
    lds[hl][dq + 6] = b.z; lds[hl][dq + 7] = b.w;
    __syncthreads();

    const int d = t >> 3, hq = (t & 7) * 8;
    ushort8v o;
    #pragma unroll
    for (int i = 0; i < 8; ++i) o[i] = f2bf_bits(lds[hq + i][d]);
    *reinterpret_cast<ushort8v*>(
        reinterpret_cast<unsigned short*>(vt) + ((size_t)bh * 32 + d) * kHW + hw0 + hq) = o;
}

// ---------------------------------------------------------------------------
// Kernel 3: LePE 5x5 depthwise conv on v (head-major in, token-major out)
// ---------------------------------------------------------------------------
__global__ __launch_bounds__(256) void lepe_kernel(
    const float* __restrict__ vb,
    const float* __restrict__ lw, const float* __restrict__ lb,
    float* __restrict__ lepe)
{
    const int c   = threadIdx.x;
    const int bhw = blockIdx.x;
    const int b   = bhw / kHW;
    const int hw  = bhw % kHW;
    const int h   = hw / kW;
    const int w   = hw % kW;
    const int head = c >> 5;
    const int d    = c & 31;

    const float* vsrc = vb + ((size_t)(b * kHeads + head) * kHW) * kHD + d;
    float acc = lb[c];
    #pragma unroll
    for (int dh = 0; dh < 5; ++dh) {
        const int h2 = h + dh - 2;
        if (h2 < 0 || h2 >= kH) continue;
        #pragma unroll
        for (int dw = 0; dw < 5; ++dw) {
            const int w2 = w + dw - 2;
            if (w2 < 0 || w2 >= kW) continue;
            acc += vsrc[(size_t)(h2 * kW + w2) * kHD] * lw[(dh * 5 + dw) * kC + c];
        }
    }
    lepe[(size_t)bhw * kC + c] = acc;
}

// ---------------------------------------------------------------------------
// Kernel 4: MFMA attention. LDS-free, no barriers.
// grid (36, 32) block 256 = 4 independent waves, each owns 16 q rows.
// S^T = mfma(K_tilej, Q^T, C=mask) -> lane holds 16 scores for q = lane&15.
// exp (no max: scores bounded ~|4|), pack bf16, shfl-redistribute to
// A-fragment layout, PV via 4 mfma into persistent f32 accumulators.
// ---------------------------------------------------------------------------
__global__ __launch_bounds__(256) void attn_mfma_kernel(
    const __hip_bfloat16* __restrict__ qb, const __hip_bfloat16* __restrict__ kb,
    const __hip_bfloat16* __restrict__ vt, const float* __restrict__ mask,
    float* __restrict__ ao)
{
    const int bh   = blockIdx.y;
    const int b    = bh >> 3;
    const int head = bh & 7;
    const int tid  = threadIdx.x;
    const int wave = tid >> 6;
    const int lane = tid & 63;
    const int lq   = lane & 15;
    const int g    = lane >> 4;
    const int q0   = blockIdx.x * 64 + wave * 16;
    const int qrow = q0 + lq;

    // Q B-fragment: lane holds Q[qrow][8g .. 8g+7]
    const bf16x8 qfrag = *reinterpret_cast<const bf16x8*>(
        reinterpret_cast<const unsigned short*>(qb) +
        ((size_t)bh * kHW + qrow) * kHD + g * 8);

    const unsigned short* kbase =
        reinterpret_cast<const unsigned short*>(kb) + (size_t)bh * kHW * kHD;
    const unsigned short* v0p =
        reinterpret_cast<const unsigned short*>(vt) + ((size_t)bh * kHD + lq) * kHW;
    const unsigned short* v1p = v0p + (size_t)16 * kHW;
    const float* mrow = mask + ((size_t)head * kHW + qrow) * kHW;

    f32x4 o0 = {0.f, 0.f, 0.f, 0.f};
    f32x4 o1 = {0.f, 0.f, 0.f, 0.f};
    float lsum = 0.f;
    const bool ghi = (g >= 2);

    for (int kt = 0; kt < kHW; kt += 64) {
        // K A-fragments (4 j tiles) + mask as MFMA C operand
        bf16x8 kf[4];
        f32x4  mc[4];
        #pragma unroll
        for (int j = 0; j < 4; ++j) {
            kf[j] = *reinterpret_cast<const bf16x8*>(
                kbase + (size_t)(kt + j * 16 + lq) * kHD + g * 8);
            mc[j] = *reinterpret_cast<const f32x4*>(mrow + kt + j * 16 + g * 4);
        }
        // V B-fragments: [h (k-half)][dh (d-half)]
        const bf16x8 va = *reinterpret_cast<const bf16x8*>(v0p + kt + g * 8);
        const bf16x8 vbf = *reinterpret_cast<const bf16x8*>(v0p + kt + 32 + g * 8);
        const bf16x8 vc = *reinterpret_cast<const bf16x8*>(v1p + kt + g * 8);
        const bf16x8 vd = *reinterpret_cast<const bf16x8*>(v1p + kt + 32 + g * 8);

        f32x4 st[4];
        #pragma unroll
        for (int j = 0; j < 4; ++j)
            st[j] = __builtin_amdgcn_mfma_f32_16x16x32_bf16(kf[j], qfrag, mc[j], 0, 0, 0);

        // exp + row-sum partial + pack to bf16 pairs (lane's q = lq)
        unsigned p32[4][2];
        #pragma unroll
        for (int j = 0; j < 4; ++j) {
            const float e0 = __expf(st[j][0]);
            const float e1 = __expf(st[j][1]);
            const float e2 = __expf(st[j][2]);
            const float e3 = __expf(st[j][3]);
            lsum += (e0 + e1) + (e2 + e3);
            p32[j][0] = (unsigned)f2bf_bits(e0) | ((unsigned)f2bf_bits(e1) << 16);
            p32[j][1] = (unsigned)f2bf_bits(e2) | ((unsigned)f2bf_bits(e3) << 16);
        }

        // redistribute P (S^T lane layout) -> PV A-fragment layout.
        // target lane (q=lq, g) element-pair t of half h needs k = 32h+8g+2t:
        //   src lane = lq + 16*(2*(g&1) + (t>>1)), register j = 2h + (g>>1), rp = t&1
        unsigned pw0[4], pw1[4];
        #pragma unroll
        for (int t = 0; t < 4; ++t) {
            const int src = lq + 16 * (2 * (g & 1) + (t >> 1));
            const unsigned a0 = __shfl(p32[0][t & 1], src);
            const unsigned a1 = __shfl(p32[1][t & 1], src);
            const unsigned b0 = __shfl(p32[2][t & 1], src);
            const unsigned b1 = __shfl(p32[3][t & 1], src);
            pw0[t] = ghi ? a1 : a0;
            pw1[t] = ghi ? b1 : b0;
        }
        uint32x4 w0 = {pw0[0], pw0[1], pw0[2], pw0[3]};
        uint32x4 w1 = {pw1[0], pw1[1], pw1[2], pw1[3]};
        const bf16x8 pa0 = __builtin_bit_cast(bf16x8, w0);
        const bf16x8 pa1 = __builtin_bit_cast(bf16x8, w1);

        o0 = __builtin_amdgcn_mfma_f32_16x16x32_bf16(pa0, va,  o0, 0, 0, 0);
        o0 = __builtin_amdgcn_mfma_f32_16x16x32_bf16(pa1, vbf, o0, 0, 0, 0);
        o1 = __builtin_amdgcn_mfma_f32_16x16x32_bf16(pa0, vc,  o1, 0, 0, 0);
        o1 = __builtin_amdgcn_mfma_f32_16x16x32_bf16(pa1, vd,  o1, 0, 0, 0);
    }

    // full row-sum for q=lq, then redistribute 1/sum to output rows (4g+r)
    lsum += __shfl_xor(lsum, 16);
    lsum += __shfl_xor(lsum, 32);
    const float rinv = 1.0f / lsum;

    #pragma unroll
    for (int r = 0; r < 4; ++r) {
        const float sc = __shfl(rinv, 4 * g + r);
        float* orow = ao + ((size_t)b * kHW + q0 + 4 * g + r) * kC + head * kHD + lq;
        orow[0]  = o0[r] * sc;
        orow[16] = o1[r] * sc;
    }
}

// ---------------------------------------------------------------------------
// Kernel 5: output projection GEMM, fusing (attn_out + lepe) @ Wout + bout
// ---------------------------------------------------------------------------
__global__ __launch_bounds__(256) void out_gemm_kernel(
    const float* __restrict__ a0, const float* __restrict__ a1,
    const float* __restrict__ Wo, const float* __restrict__ bo,
    float* __restrict__ out)
{
    __shared__ __align__(16) float As[16][65];
    __shared__ __align__(16) float Bs[16][65];

    const int tid = threadIdx.x;
    const int mBase = blockIdx.x * 64;
    const int nBase = blockIdx.y * 64;

    const int tx = tid & 15;
    const int ty = tid >> 4;

    const int lm  = tid >> 2;
    const int lk  = (tid & 3) * 4;
    const int lbk = tid >> 4;
    const int lbn = (tid & 15) * 4;

    float acc[4][4] = {};

    for (int k0 = 0; k0 < 256; k0 += 16) {
        const size_t aoff = (size_t)(mBase + lm) * 256 + k0 + lk;
        const float4 av0 = *reinterpret_cast<const float4*>(&a0[aoff]);
        const float4 av1 = *reinterpret_cast<const float4*>(&a1[aoff]);
        As[lk + 0][lm] = av0.x + av1.x; As[lk + 1][lm] = av0.y + av1.y;
        As[lk + 2][lm] = av0.z + av1.z; As[lk + 3][lm] = av0.w + av1.w;

        const float4 bv4 = *reinterpret_cast<const float4*>(
            &Wo[(size_t)(k0 + lbk) * 256 + nBase + lbn]);
        Bs[lbk][lbn + 0] = bv4.x; Bs[lbk][lbn + 1] = bv4.y;
        Bs[lbk][lbn + 2] = bv4.z; Bs[lbk][lbn + 3] = bv4.w;
        __syncthreads();

        #pragma unroll
        for (int kk = 0; kk < 16; ++kk) {
            float a[4], bb[4];
            #pragma unroll
            for (int i = 0; i < 4; ++i) a[i] = As[kk][ty * 4 + i];
            #pragma unroll
            for (int j = 0; j < 4; ++j) bb[j] = Bs[kk][tx * 4 + j];
            #pragma unroll
            for (int i = 0; i < 4; ++i)
                #pragma unroll
                for (int j = 0; j < 4; ++j)
                    acc[i][j] += a[i] * bb[j];
        }
        __syncthreads();
    }

    #pragma unroll
    for (int i = 0; i < 4; ++i) {
        const int m = mBase + ty * 4 + i;
        #pragma unroll
        for (int j = 0; j < 4; ++j) {
            const int n = nBase + tx * 4 + j;
            out[(size_t)m * 256 + n] = acc[i][j] + bo[n];
        }
    }
}

// ---------------------------------------------------------------------------
extern "C" void kernel_launch(void* const* d_in, const int* in_sizes, int n_in,
                              void* d_out, int out_size, void* d_ws, size_t ws_size,
                              hipStream_t stream)
{
    const float* x    = (const float*)d_in[0];
    const float* sinb = (const float*)d_in[1];
    const float* cosb = (const float*)d_in[2];
    const float* mask = (const float*)d_in[3];
    const float* Wq   = (const float*)d_in[4];
    const float* bq   = (const float*)d_in[5];
    const float* Wk   = (const float*)d_in[6];
    const float* bk   = (const float*)d_in[7];
    const float* Wv   = (const float*)d_in[8];
    const float* bv   = (const float*)d_in[9];
    const float* lw   = (const float*)d_in[10];
    const float* lb   = (const float*)d_in[11];
    const float* Wo   = (const float*)d_in[12];
    const float* bo   = (const float*)d_in[13];
    float* out = (float*)d_out;

    const size_t NT = (size_t)kB * kHeads * kHW * kHD;  // 2359296 per tensor
    char* base = (char*)d_ws;
    float* vb   = (float*)base;             base += NT * 4;
    float* lepe = (float*)base;             base += NT * 4;
    float* ao   = (float*)base;             base += NT * 4;
    __hip_bfloat16* qbh = (__hip_bfloat16*)base; base += NT * 2;
    __hip_bfloat16* kbh = (__hip_bfloat16*)base; base += NT * 2;
    __hip_bfloat16* vt  = (__hip_bfloat16*)base; base += NT * 2;

    qkv_gemm_kernel<<<dim3(144, 4, 3), 256, 0, stream>>>(
        x, Wq, bq, Wk, bk, Wv, bv, sinb, cosb, qbh, kbh, vb);
    vt_kernel<<<dim3(36, 32), 256, 0, stream>>>(vb, vt);
    lepe_kernel<<<dim3(9216), 256, 0, stream>>>(vb, lw, lb, lepe);
    attn_mfma_kernel<<<dim3(36, 32), 256, 0, stream>>>(qbh, kbh, vt, mask, ao);
    out_gemm_kernel<<<dim3(144, 4), 256, 0, stream>>>(ao, lepe, Wo, bo, out);
}